// Round 14
// baseline (309.996 us; speedup 1.0000x reference)
//
#include <hip/hip_runtime.h>
#include <hip/hip_bf16.h>
#include <stdint.h>

typedef unsigned short u16;
typedef __attribute__((ext_vector_type(8))) short short8;
typedef __attribute__((ext_vector_type(4))) float f32x4;

#define DIM 128
#define CAP 64   // per-node bucket capacity; deg ~ Poisson(16), P(deg>=64) ~ 2e-18/node

__device__ __forceinline__ float bflo(uint32_t v) {
    uint32_t b = v << 16;
    float f; __builtin_memcpy(&f, &b, 4); return f;
}
__device__ __forceinline__ float bfhi(uint32_t v) {
    uint32_t b = v & 0xffff0000u;
    float f; __builtin_memcpy(&f, &b, 4); return f;
}
__device__ __forceinline__ u16 f2bf(float f) {
    uint32_t x; __builtin_memcpy(&x, &f, 4);
    uint32_t r = (x + 0x7fffu + ((x >> 16) & 1u)) >> 16;
    return (u16)r;
}
__device__ __forceinline__ uint32_t pack2bf(float a, float b) {
    return (uint32_t)f2bf(a) | ((uint32_t)f2bf(b) << 16);
}

// ---------------- sort-based CSR build (no per-edge global atomics) ----------------

__global__ __launch_bounds__(256) void k_bin1(
    const int* __restrict__ src, const int* __restrict__ dst,
    uint32_t* __restrict__ gCur, uint32_t* __restrict__ groupBuf,
    int E, int ngrp, int gcap)
{
    __shared__ uint32_t hcnt[512];
    __shared__ uint32_t hbase[512];
    __shared__ uint32_t hcur[512];
    int nb = gridDim.x;
    int per = (E + nb - 1) / nb;
    int lo = blockIdx.x * per;
    int hi = lo + per; if (hi > E) hi = E;

    for (int t = threadIdx.x; t < ngrp; t += 256) { hcnt[t] = 0; hcur[t] = 0; }
    __syncthreads();

    for (int i = lo + threadIdx.x; i < hi; i += 256)
        atomicAdd(&hcnt[((uint32_t)dst[i]) >> 8], 1u);
    __syncthreads();

    int rot = (blockIdx.x * 37) % (ngrp > 0 ? ngrp : 1);
    for (int k = threadIdx.x; k < ngrp; k += 256) {
        int t = k + rot; if (t >= ngrp) t -= ngrp;
        uint32_t c = hcnt[t];
        hbase[t] = c ? atomicAdd(&gCur[t], c) : 0u;
    }
    __syncthreads();

    for (int i = lo + threadIdx.x; i < hi; i += 256) {
        uint32_t d = (uint32_t)dst[i];
        uint32_t g = d >> 8;
        uint32_t off = hbase[g] + atomicAdd(&hcur[g], 1u);
        if (off < (uint32_t)gcap)
            groupBuf[(size_t)g * gcap + off] = (uint32_t)src[i] | ((d & 255u) << 20);
    }
}

__global__ __launch_bounds__(256) void k_bin2(
    const uint32_t* __restrict__ groupBuf, const uint32_t* __restrict__ gCur,
    uint32_t* __restrict__ bucket, uint32_t* __restrict__ cnt,
    int N, int gcap)
{
    __shared__ uint32_t ncur[256];
    int g = blockIdx.x;
    ncur[threadIdx.x] = 0;
    __syncthreads();
    uint32_t m = gCur[g]; if (m > (uint32_t)gcap) m = gcap;
    int nodebase = g << 8;
    const uint32_t* buf = groupBuf + (size_t)g * gcap;
    for (uint32_t i = threadIdx.x; i < m; i += 256) {
        uint32_t v = buf[i];
        uint32_t nl = v >> 20;
        uint32_t s = v & 0xFFFFFu;
        uint32_t pos = atomicAdd(&ncur[nl], 1u);   // LDS atomic
        if (pos < CAP) bucket[(size_t)(nodebase + (int)nl) * CAP + pos] = s;
    }
    __syncthreads();
    int node = nodebase + threadIdx.x;
    if (node < N) cnt[node] = ncur[threadIdx.x];
}

// ---------------- feature cast f32 -> bf16 (once per call) ----------------

__global__ void k_cast(const float* __restrict__ in, uint32_t* __restrict__ out, int n4) {
    int i = blockIdx.x * blockDim.x + threadIdx.x;
    int stride = gridDim.x * blockDim.x;
    const float4* in4 = (const float4*)in;
    uint2* out2 = (uint2*)out;
    for (; i < n4; i += stride) {
        float4 v = in4[i];
        uint2 r;
        r.x = pack2bf(v.x, v.y);
        r.y = pack2bf(v.z, v.w);
        out2[i] = r;
    }
}

// ---------------- zero row N of X0 and X (invalid-slot target row) ----------------

__global__ void k_zero_row(uint32_t* __restrict__ a, uint32_t* __restrict__ b, int N) {
    int t = threadIdx.x;
    if (t < 64) a[(size_t)N * 64 + t] = 0u;
    else        b[(size_t)N * 64 + (t - 64)] = 0u;
}

// ---------------- weight transpose f32 -> bf16 (once per call) ----------------

__global__ void k_transpose3(const float* __restrict__ w0, const float* __restrict__ w1,
                             const float* __restrict__ w2, u16* __restrict__ t0,
                             u16* __restrict__ t1, u16* __restrict__ t2) {
    const float* w = blockIdx.x == 0 ? w0 : (blockIdx.x == 1 ? w1 : w2);
    u16* o = blockIdx.x == 0 ? t0 : (blockIdx.x == 1 ? t1 : t2);
    for (int idx = threadIdx.x; idx < DIM * DIM; idx += blockDim.x) {
        int r = idx >> 7, c = idx & 127;
        o[c * DIM + r] = f2bf(w[idx]);
    }
}

// ---------------- gather (segment_sum pull) + LayerNorm fused ----------------
// One wave per node; lane handles dims {2l, 2l+1}; f32 accumulation.
// Scalar addressing (readfirstlane node -> SGPR everything). Groups of 16 while
// fully valid (no per-slot select); single partial group at 4-granularity
// (issue-all-then-accumulate). Wasted zero-row loads: ~42% -> ~9%.

__global__ __launch_bounds__(256) void k_gather_ln(
    const uint32_t* __restrict__ xin, const uint32_t* __restrict__ cnt,
    const uint32_t* __restrict__ bucket,
    const int* __restrict__ src, const int* __restrict__ dst,
    const float* __restrict__ gamma, const float* __restrict__ beta,
    uint32_t* __restrict__ h, int N, int E)
{
    int w = threadIdx.x >> 6, l = threadIdx.x & 63;
    // provably wave-uniform node index -> scalar addressing throughout
    int node = __builtin_amdgcn_readfirstlane(blockIdx.x * 4 + w);
    if (node >= N) return;
    uint32_t c = cnt[node];            // uniform -> s_load
    float a0 = 0.f, a1 = 0.f;

    if (__builtin_expect(c > CAP, 0)) {
        // overflow fallback: raw edge scan (never in practice)
        for (int e = 0; e < E; ++e) {
            if (dst[e] == node) {
                uint32_t v = xin[(size_t)src[e] * 64 + l];
                a0 += bflo(v); a1 += bfhi(v);
            }
        }
    } else {
        // lane l holds bucket slot l (slots >= c are garbage, never dereferenced)
        uint32_t bktv = bucket[(size_t)node * CAP + l];
#pragma unroll
        for (int g = 0; g < 4; ++g) {
            if ((uint32_t)(g * 16 + 16) <= c) {
                // full group: every slot valid -> no select at all
                uint32_t v[16];
#pragma unroll
                for (int i = 0; i < 16; ++i) {
                    const int SLOT = g * 16 + i;
                    uint32_t su = (uint32_t)__builtin_amdgcn_readfirstlane(
                        (int)((uint32_t)__builtin_amdgcn_readlane(bktv, SLOT)));
                    v[i] = (xin + (size_t)su * 64)[l];
                }
#pragma unroll
                for (int i = 0; i < 16; ++i) { a0 += bflo(v[i]); a1 += bfhi(v[i]); }
            } else if ((uint32_t)(g * 16) < c) {
                // partial group: 4-granularity sub-blocks, issue-all then accumulate
                uint32_t v[16];
#pragma unroll
                for (int q = 0; q < 4; ++q) {
                    if ((uint32_t)(g * 16 + q * 4) < c) {
#pragma unroll
                        for (int i = 0; i < 4; ++i) {
                            const int SLOT = g * 16 + q * 4 + i;
                            uint32_t su = (uint32_t)__builtin_amdgcn_readfirstlane(
                                (int)((uint32_t)__builtin_amdgcn_readlane(bktv, SLOT)));
                            su = ((uint32_t)SLOT < c) ? su : (uint32_t)N;  // s_cselect -> zero row
                            v[q * 4 + i] = (xin + (size_t)su * 64)[l];
                        }
                    }
                }
#pragma unroll
                for (int q = 0; q < 4; ++q) {
                    if ((uint32_t)(g * 16 + q * 4) < c) {
#pragma unroll
                        for (int i = 0; i < 4; ++i) {
                            a0 += bflo(v[q * 4 + i]); a1 += bfhi(v[q * 4 + i]);
                        }
                    }
                }
            }
        }
    }

    float sum = a0 + a1;
    float sq  = a0 * a0 + a1 * a1;
    for (int off = 32; off; off >>= 1) {
        sum += __shfl_xor(sum, off, 64);
        sq  += __shfl_xor(sq,  off, 64);
    }
    float mean = sum * (1.f / 128.f);
    float var  = sq * (1.f / 128.f) - mean * mean;
    float rs   = rsqrtf(var + 1e-5f);
    float g0 = gamma[2 * l], g1 = gamma[2 * l + 1];
    float b0 = beta[2 * l],  b1 = beta[2 * l + 1];
    float h0 = (a0 - mean) * rs * g0 + b0;
    float h1 = (a1 - mean) * rs * g1 + b1;
    h[(size_t)node * 64 + l] = pack2bf(h0, h1);
}

// ---------------- persistent GEMM with A-prefetch ----------------
// Grid-stride over 32-row tiles; B-fragments + bias hoisted; next tile's
// A-fragments issued before current tile's MFMAs (software pipeline).

template <int RELU, int OUTF32>
__global__ __launch_bounds__(256) void k_gemm(
    const u16* __restrict__ h, const u16* __restrict__ wt,
    const float* __restrict__ bias, void* __restrict__ outp, int N)
{
    int w = threadIdx.x >> 6, l = threadIdx.x & 63;
    int colbase = (w >> 1) * 64;
    int lr = l & 15, lg = l >> 4;

    short8 bfrag[4][4];
    float bv[4];
#pragma unroll
    for (int ct = 0; ct < 4; ++ct) {
        bv[ct] = bias[colbase + ct * 16 + lr];
#pragma unroll
        for (int kc = 0; kc < 4; ++kc)
            bfrag[ct][kc] = *(const short8*)(wt + (size_t)(colbase + ct * 16 + lr) * DIM + kc * 32 + lg * 8);
    }

    int ntiles = (N + 31) / 32;
    int t = blockIdx.x;
    if (t >= ntiles) return;

    auto loadA = [&](int tt, short8* af) {
        int ar = tt * 32 + 16 * (w & 1) + lr;
        if (ar > N - 1) ar = N - 1;
#pragma unroll
        for (int kc = 0; kc < 4; ++kc)
            af[kc] = *(const short8*)(h + (size_t)ar * DIM + kc * 32 + lg * 8);
    };

    short8 afrag[4];
    loadA(t, afrag);

    while (true) {
        int tn = t + (int)gridDim.x;
        bool has = tn < ntiles;
        short8 anext[4];
        if (has) loadA(tn, anext);   // issued before current tile's MFMAs

        int row0 = t * 32 + 16 * (w & 1);
#pragma unroll
        for (int ct = 0; ct < 4; ++ct) {
            f32x4 a = {0.f, 0.f, 0.f, 0.f};
#pragma unroll
            for (int kc = 0; kc < 4; ++kc)
                a = __builtin_amdgcn_mfma_f32_16x16x32_bf16(afrag[kc], bfrag[ct][kc], a, 0, 0, 0);
            int col = colbase + ct * 16 + lr;
#pragma unroll
            for (int j = 0; j < 4; ++j) {
                int row = row0 + lg * 4 + j;
                float v = a[j] + bv[ct];
                if (RELU) v = fmaxf(v, 0.f);
                if (row < N) {
                    if (OUTF32) ((float*)outp)[(size_t)row * DIM + col] = v;
                    else        ((u16*)outp)[(size_t)row * DIM + col] = f2bf(v);
                }
            }
        }

        if (!has) break;
#pragma unroll
        for (int kc = 0; kc < 4; ++kc) afrag[kc] = anext[kc];
        t = tn;
    }
}

// ---------------- launch ----------------

extern "C" void kernel_launch(void* const* d_in, const int* in_sizes, int n_in,
                              void* d_out, int out_size, void* d_ws, size_t ws_size,
                              hipStream_t stream) {
    const float* feat = (const float*)d_in[0];
    const int* src  = (const int*)d_in[1];
    const int* dst  = (const int*)d_in[2];
    const float* g1 = (const float*)d_in[3],  *be1 = (const float*)d_in[4];
    const float* W1 = (const float*)d_in[5],  *b1  = (const float*)d_in[6];
    const float* g2 = (const float*)d_in[7],  *be2 = (const float*)d_in[8];
    const float* W2 = (const float*)d_in[9],  *b2  = (const float*)d_in[10];
    const float* g3 = (const float*)d_in[11], *be3 = (const float*)d_in[12];
    const float* W3 = (const float*)d_in[13], *b3  = (const float*)d_in[14];

    int N = in_sizes[0] / DIM;
    int E = in_sizes[1];
    float* out = (float*)d_out;

    int ngrp = (N + 255) >> 8;                 // 391 for N=100000 (max 512)
    int gcap = (E / (ngrp > 0 ? ngrp : 1)) * 3 / 2 + 1024;

    char* ws = (char*)d_ws;
    auto alloc = [&](size_t bytes) {
        char* p = ws;
        ws += (bytes + 255) & ~(size_t)255;
        return p;
    };
    uint32_t* gCur     = (uint32_t*)alloc((size_t)ngrp * 4);
    uint32_t* groupBuf = (uint32_t*)alloc((size_t)ngrp * gcap * 4);
    uint32_t* cnt      = (uint32_t*)alloc((size_t)N * 4);
    uint32_t* bucket   = (uint32_t*)alloc((size_t)N * CAP * 4);
    u16* wt1 = (u16*)alloc(DIM * DIM * 2);
    u16* wt2 = (u16*)alloc(DIM * DIM * 2);
    u16* wt3 = (u16*)alloc(DIM * DIM * 2);
    // N+1 rows: row N is the zero row targeted by invalid slots
    uint32_t* X0 = (uint32_t*)alloc((size_t)(N + 1) * 64 * 4);
    uint32_t* H  = (uint32_t*)alloc((size_t)(N + 1) * 64 * 4);
    uint32_t* X  = (uint32_t*)alloc((size_t)(N + 1) * 64 * 4);

    hipMemsetAsync(gCur, 0, (size_t)ngrp * 4, stream);
    k_bin1<<<256, 256, 0, stream>>>(src, dst, gCur, groupBuf, E, ngrp, gcap);
    k_bin2<<<ngrp, 256, 0, stream>>>(groupBuf, gCur, bucket, cnt, N, gcap);
    k_transpose3<<<3, 256, 0, stream>>>(W1, W2, W3, wt1, wt2, wt3);
    k_cast<<<1024, 256, 0, stream>>>(feat, X0, N * 32);
    k_zero_row<<<1, 128, 0, stream>>>(X0, X, N);

    int gblocks = (N + 3) / 4;

    // gather reads X0/X (+ zero row N), writes H; gemm reads H, writes X — never aliased
    k_gather_ln<<<gblocks, 256, 0, stream>>>(X0, cnt, bucket, src, dst, g1, be1, H, N, E);
    k_gemm<1, 0><<<512, 256, 0, stream>>>((const u16*)H, wt1, b1, X, N);
    k_gather_ln<<<gblocks, 256, 0, stream>>>(X, cnt, bucket, src, dst, g2, be2, H, N, E);
    k_gemm<1, 0><<<512, 256, 0, stream>>>((const u16*)H, wt2, b2, X, N);
    k_gather_ln<<<gblocks, 256, 0, stream>>>(X, cnt, bucket, src, dst, g3, be3, H, N, E);
    k_gemm<0, 1><<<512, 256, 0, stream>>>((const u16*)H, wt3, b3, out, N);
}

// Round 15
// 305.359 us; speedup vs baseline: 1.0152x; 1.0152x over previous
//
#include <hip/hip_runtime.h>
#include <hip/hip_bf16.h>
#include <stdint.h>

typedef unsigned short u16;
typedef __attribute__((ext_vector_type(8))) short short8;
typedef __attribute__((ext_vector_type(4))) float f32x4;

#define DIM 128
#define CAP 64   // per-node bucket capacity; deg ~ Poisson(16), P(deg>=64) ~ 2e-18/node

__device__ __forceinline__ float bflo(uint32_t v) {
    uint32_t b = v << 16;
    float f; __builtin_memcpy(&f, &b, 4); return f;
}
__device__ __forceinline__ float bfhi(uint32_t v) {
    uint32_t b = v & 0xffff0000u;
    float f; __builtin_memcpy(&f, &b, 4); return f;
}
__device__ __forceinline__ u16 f2bf(float f) {
    uint32_t x; __builtin_memcpy(&x, &f, 4);
    uint32_t r = (x + 0x7fffu + ((x >> 16) & 1u)) >> 16;
    return (u16)r;
}
__device__ __forceinline__ uint32_t pack2bf(float a, float b) {
    return (uint32_t)f2bf(a) | ((uint32_t)f2bf(b) << 16);
}

// ---------------- sort-based CSR build (no per-edge global atomics) ----------------

__global__ __launch_bounds__(256) void k_bin1(
    const int* __restrict__ src, const int* __restrict__ dst,
    uint32_t* __restrict__ gCur, uint32_t* __restrict__ groupBuf,
    int E, int ngrp, int gcap)
{
    __shared__ uint32_t hcnt[512];
    __shared__ uint32_t hbase[512];
    __shared__ uint32_t hcur[512];
    int nb = gridDim.x;
    int per = (E + nb - 1) / nb;
    int lo = blockIdx.x * per;
    int hi = lo + per; if (hi > E) hi = E;

    for (int t = threadIdx.x; t < ngrp; t += 256) { hcnt[t] = 0; hcur[t] = 0; }
    __syncthreads();

    for (int i = lo + threadIdx.x; i < hi; i += 256)
        atomicAdd(&hcnt[((uint32_t)dst[i]) >> 8], 1u);
    __syncthreads();

    int rot = (blockIdx.x * 37) % (ngrp > 0 ? ngrp : 1);
    for (int k = threadIdx.x; k < ngrp; k += 256) {
        int t = k + rot; if (t >= ngrp) t -= ngrp;
        uint32_t c = hcnt[t];
        hbase[t] = c ? atomicAdd(&gCur[t], c) : 0u;
    }
    __syncthreads();

    for (int i = lo + threadIdx.x; i < hi; i += 256) {
        uint32_t d = (uint32_t)dst[i];
        uint32_t g = d >> 8;
        uint32_t off = hbase[g] + atomicAdd(&hcur[g], 1u);
        if (off < (uint32_t)gcap)
            groupBuf[(size_t)g * gcap + off] = (uint32_t)src[i] | ((d & 255u) << 20);
    }
}

__global__ __launch_bounds__(256) void k_bin2(
    const uint32_t* __restrict__ groupBuf, const uint32_t* __restrict__ gCur,
    uint32_t* __restrict__ bucket, uint32_t* __restrict__ cnt,
    int N, int gcap)
{
    __shared__ uint32_t ncur[256];
    int g = blockIdx.x;
    ncur[threadIdx.x] = 0;
    __syncthreads();
    uint32_t m = gCur[g]; if (m > (uint32_t)gcap) m = gcap;
    int nodebase = g << 8;
    const uint32_t* buf = groupBuf + (size_t)g * gcap;
    for (uint32_t i = threadIdx.x; i < m; i += 256) {
        uint32_t v = buf[i];
        uint32_t nl = v >> 20;
        uint32_t s = v & 0xFFFFFu;
        uint32_t pos = atomicAdd(&ncur[nl], 1u);   // LDS atomic
        if (pos < CAP) bucket[(size_t)(nodebase + (int)nl) * CAP + pos] = s;
    }
    __syncthreads();
    int node = nodebase + threadIdx.x;
    if (node < N) cnt[node] = ncur[threadIdx.x];
}

// ---------------- prep: weight transpose + feature cast + zero rows (one launch) ----

__global__ void k_prep(const float* __restrict__ feat, uint32_t* __restrict__ X0,
                       uint32_t* __restrict__ X, int N,
                       const float* __restrict__ W1, const float* __restrict__ W2,
                       const float* __restrict__ W3,
                       u16* __restrict__ t0, u16* __restrict__ t1, u16* __restrict__ t2)
{
    int b = blockIdx.x;
    if (b < 3) {
        const float* w = b == 0 ? W1 : (b == 1 ? W2 : W3);
        u16* o = b == 0 ? t0 : (b == 1 ? t1 : t2);
        for (int idx = threadIdx.x; idx < DIM * DIM; idx += blockDim.x) {
            int r = idx >> 7, c = idx & 127;
            o[c * DIM + r] = f2bf(w[idx]);
        }
    } else if (b == 3) {
        int t = threadIdx.x;
        if (t < 64) X0[(size_t)N * 64 + t] = 0u;
        else if (t < 128) X[(size_t)N * 64 + (t - 64)] = 0u;
    } else {
        int n4 = N * 32;
        int i = (b - 4) * 256 + threadIdx.x;
        int stride = (gridDim.x - 4) * 256;
        const float4* in4 = (const float4*)feat;
        uint2* out2 = (uint2*)X0;
        for (; i < n4; i += stride) {
            float4 v = in4[i];
            uint2 r;
            r.x = pack2bf(v.x, v.y);
            r.y = pack2bf(v.z, v.w);
            out2[i] = r;
        }
    }
}

// ---------------- gather (segment_sum pull) + LayerNorm fused ----------------
// TWO nodes per wave (sequential scalar-addressed gathers, identical to the
// proven r13 structure) + INTERLEAVED LN epilogue: 4 independent reduce chains
// amortize the 6-level shfl_xor latency over 2 nodes; half the waves.

__global__ __launch_bounds__(256) void k_gather_ln(
    const uint32_t* __restrict__ xin, const uint32_t* __restrict__ cnt,
    const uint32_t* __restrict__ bucket,
    const int* __restrict__ src, const int* __restrict__ dst,
    const float* __restrict__ gamma, const float* __restrict__ beta,
    uint32_t* __restrict__ h, int N, int E)
{
    int w = threadIdx.x >> 6, l = threadIdx.x & 63;
    int node0 = __builtin_amdgcn_readfirstlane(2 * (blockIdx.x * 4 + w));
    if (node0 >= N) return;
    int node1 = node0 + 1;
    bool has1 = node1 < N;
    uint32_t c0 = cnt[node0];
    uint32_t c1 = has1 ? cnt[node1] : 0u;
    float a0 = 0.f, a1 = 0.f, b0 = 0.f, b1 = 0.f;

    if (__builtin_expect(c0 > CAP || c1 > CAP, 0)) {
        // overflow fallback: raw edge scan (never in practice)
        for (int e = 0; e < E; ++e) {
            int d = dst[e];
            if (d == node0) { uint32_t v = xin[(size_t)src[e] * 64 + l]; a0 += bflo(v); a1 += bfhi(v); }
            else if (d == node1) { uint32_t v = xin[(size_t)src[e] * 64 + l]; b0 += bflo(v); b1 += bfhi(v); }
        }
    } else {
        // ---- node0 gather (scalar addressing, 16-deep) ----
        {
            uint32_t bktv = bucket[(size_t)node0 * CAP + l];
#pragma unroll
            for (int g = 0; g < 4; ++g) {
                if ((uint32_t)(g * 16) < c0) {
                    uint32_t v[16];
#pragma unroll
                    for (int i = 0; i < 16; ++i) {
                        const int SLOT = g * 16 + i;
                        uint32_t su = (uint32_t)__builtin_amdgcn_readfirstlane(
                            (int)((uint32_t)__builtin_amdgcn_readlane(bktv, SLOT)));
                        su = ((uint32_t)SLOT < c0) ? su : (uint32_t)N;
                        v[i] = (xin + (size_t)su * 64)[l];
                    }
#pragma unroll
                    for (int i = 0; i < 16; ++i) { a0 += bflo(v[i]); a1 += bfhi(v[i]); }
                }
            }
        }
        // ---- node1 gather ----
        if (has1) {
            uint32_t bktv = bucket[(size_t)node1 * CAP + l];
#pragma unroll
            for (int g = 0; g < 4; ++g) {
                if ((uint32_t)(g * 16) < c1) {
                    uint32_t v[16];
#pragma unroll
                    for (int i = 0; i < 16; ++i) {
                        const int SLOT = g * 16 + i;
                        uint32_t su = (uint32_t)__builtin_amdgcn_readfirstlane(
                            (int)((uint32_t)__builtin_amdgcn_readlane(bktv, SLOT)));
                        su = ((uint32_t)SLOT < c1) ? su : (uint32_t)N;
                        v[i] = (xin + (size_t)su * 64)[l];
                    }
#pragma unroll
                    for (int i = 0; i < 16; ++i) { b0 += bflo(v[i]); b1 += bfhi(v[i]); }
                }
            }
        }
    }

    // ---- interleaved LN epilogue: 4 independent reduce chains ----
    float sA = a0 + a1, qA = a0 * a0 + a1 * a1;
    float sB = b0 + b1, qB = b0 * b0 + b1 * b1;
    for (int off = 32; off; off >>= 1) {
        sA += __shfl_xor(sA, off, 64);
        sB += __shfl_xor(sB, off, 64);
        qA += __shfl_xor(qA, off, 64);
        qB += __shfl_xor(qB, off, 64);
    }
    float gg0 = gamma[2 * l], gg1 = gamma[2 * l + 1];
    float bb0 = beta[2 * l],  bb1 = beta[2 * l + 1];
    {
        float mean = sA * (1.f / 128.f);
        float var  = qA * (1.f / 128.f) - mean * mean;
        float rs   = rsqrtf(var + 1e-5f);
        h[(size_t)node0 * 64 + l] =
            pack2bf((a0 - mean) * rs * gg0 + bb0, (a1 - mean) * rs * gg1 + bb1);
    }
    if (has1) {
        float mean = sB * (1.f / 128.f);
        float var  = qB * (1.f / 128.f) - mean * mean;
        float rs   = rsqrtf(var + 1e-5f);
        h[(size_t)node1 * 64 + l] =
            pack2bf((b0 - mean) * rs * gg0 + bb0, (b1 - mean) * rs * gg1 + bb1);
    }
}

// ---------------- persistent GEMM with A-prefetch ----------------

template <int RELU, int OUTF32>
__global__ __launch_bounds__(256) void k_gemm(
    const u16* __restrict__ h, const u16* __restrict__ wt,
    const float* __restrict__ bias, void* __restrict__ outp, int N)
{
    int w = threadIdx.x >> 6, l = threadIdx.x & 63;
    int colbase = (w >> 1) * 64;
    int lr = l & 15, lg = l >> 4;

    short8 bfrag[4][4];
    float bv[4];
#pragma unroll
    for (int ct = 0; ct < 4; ++ct) {
        bv[ct] = bias[colbase + ct * 16 + lr];
#pragma unroll
        for (int kc = 0; kc < 4; ++kc)
            bfrag[ct][kc] = *(const short8*)(wt + (size_t)(colbase + ct * 16 + lr) * DIM + kc * 32 + lg * 8);
    }

    int ntiles = (N + 31) / 32;
    int t = blockIdx.x;
    if (t >= ntiles) return;

    auto loadA = [&](int tt, short8* af) {
        int ar = tt * 32 + 16 * (w & 1) + lr;
        if (ar > N - 1) ar = N - 1;
#pragma unroll
        for (int kc = 0; kc < 4; ++kc)
            af[kc] = *(const short8*)(h + (size_t)ar * DIM + kc * 32 + lg * 8);
    };

    short8 afrag[4];
    loadA(t, afrag);

    while (true) {
        int tn = t + (int)gridDim.x;
        bool has = tn < ntiles;
        short8 anext[4];
        if (has) loadA(tn, anext);

        int row0 = t * 32 + 16 * (w & 1);
#pragma unroll
        for (int ct = 0; ct < 4; ++ct) {
            f32x4 a = {0.f, 0.f, 0.f, 0.f};
#pragma unroll
            for (int kc = 0; kc < 4; ++kc)
                a = __builtin_amdgcn_mfma_f32_16x16x32_bf16(afrag[kc], bfrag[ct][kc], a, 0, 0, 0);
            int col = colbase + ct * 16 + lr;
#pragma unroll
            for (int j = 0; j < 4; ++j) {
                int row = row0 + lg * 4 + j;
                float v = a[j] + bv[ct];
                if (RELU) v = fmaxf(v, 0.f);
                if (row < N) {
                    if (OUTF32) ((float*)outp)[(size_t)row * DIM + col] = v;
                    else        ((u16*)outp)[(size_t)row * DIM + col] = f2bf(v);
                }
            }
        }

        if (!has) break;
#pragma unroll
        for (int kc = 0; kc < 4; ++kc) afrag[kc] = anext[kc];
        t = tn;
    }
}

// ---------------- launch ----------------

extern "C" void kernel_launch(void* const* d_in, const int* in_sizes, int n_in,
                              void* d_out, int out_size, void* d_ws, size_t ws_size,
                              hipStream_t stream) {
    const float* feat = (const float*)d_in[0];
    const int* src  = (const int*)d_in[1];
    const int* dst  = (const int*)d_in[2];
    const float* g1 = (const float*)d_in[3],  *be1 = (const float*)d_in[4];
    const float* W1 = (const float*)d_in[5],  *b1  = (const float*)d_in[6];
    const float* g2 = (const float*)d_in[7],  *be2 = (const float*)d_in[8];
    const float* W2 = (const float*)d_in[9],  *b2  = (const float*)d_in[10];
    const float* g3 = (const float*)d_in[11], *be3 = (const float*)d_in[12];
    const float* W3 = (const float*)d_in[13], *b3  = (const float*)d_in[14];

    int N = in_sizes[0] / DIM;
    int E = in_sizes[1];
    float* out = (float*)d_out;

    int ngrp = (N + 255) >> 8;                 // 391 for N=100000 (max 512)
    int gcap = (E / (ngrp > 0 ? ngrp : 1)) * 3 / 2 + 1024;
    int npair = (N + 1) / 2;

    char* ws = (char*)d_ws;
    auto alloc = [&](size_t bytes) {
        char* p = ws;
        ws += (bytes + 255) & ~(size_t)255;
        return p;
    };
    uint32_t* gCur     = (uint32_t*)alloc((size_t)ngrp * 4);
    uint32_t* groupBuf = (uint32_t*)alloc((size_t)ngrp * gcap * 4);
    uint32_t* cnt      = (uint32_t*)alloc((size_t)N * 4);
    uint32_t* bucket   = (uint32_t*)alloc((size_t)N * CAP * 4);
    u16* wt1 = (u16*)alloc(DIM * DIM * 2);
    u16* wt2 = (u16*)alloc(DIM * DIM * 2);
    u16* wt3 = (u16*)alloc(DIM * DIM * 2);
    // N+1 rows: row N is the zero row targeted by invalid slots
    uint32_t* X0 = (uint32_t*)alloc((size_t)(N + 1) * 64 * 4);
    uint32_t* H  = (uint32_t*)alloc((size_t)(N + 1) * 64 * 4);
    uint32_t* X  = (uint32_t*)alloc((size_t)(N + 1) * 64 * 4);

    hipMemsetAsync(gCur, 0, (size_t)ngrp * 4, stream);
    k_bin1<<<512, 256, 0, stream>>>(src, dst, gCur, groupBuf, E, ngrp, gcap);
    k_bin2<<<ngrp, 256, 0, stream>>>(groupBuf, gCur, bucket, cnt, N, gcap);
    k_prep<<<1028, 256, 0, stream>>>(feat, X0, X, N, W1, W2, W3, wt1, wt2, wt3);

    int gblocks = (npair + 3) / 4;

    // gather reads X0/X (+ zero row N), writes H; gemm reads H, writes X — never aliased
    k_gather_ln<<<gblocks, 256, 0, stream>>>(X0, cnt, bucket, src, dst, g1, be1, H, N, E);
    k_gemm<1, 0><<<512, 256, 0, stream>>>((const u16*)H, wt1, b1, X, N);
    k_gather_ln<<<gblocks, 256, 0, stream>>>(X, cnt, bucket, src, dst, g2, be2, H, N, E);
    k_gemm<1, 0><<<512, 256, 0, stream>>>((const u16*)H, wt2, b2, X, N);
    k_gather_ln<<<gblocks, 256, 0, stream>>>(X, cnt, bucket, src, dst, g3, be3, H, N, E);
    k_gemm<0, 1><<<512, 256, 0, stream>>>((const u16*)H, wt3, b3, out, N);
}

// Round 16
// 291.375 us; speedup vs baseline: 1.0639x; 1.0480x over previous
//
#include <hip/hip_runtime.h>
#include <hip/hip_bf16.h>
#include <stdint.h>

typedef unsigned short u16;
typedef __attribute__((ext_vector_type(8))) short short8;
typedef __attribute__((ext_vector_type(4))) float f32x4;

#define DIM 128
#define CAP 64   // per-node bucket capacity; deg ~ Poisson(16), P(deg>=64) ~ 2e-18/node
#define LROW 68  // LDS row stride in u32 (272B)

__device__ __forceinline__ float bflo(uint32_t v) {
    uint32_t b = v << 16;
    float f; __builtin_memcpy(&f, &b, 4); return f;
}
__device__ __forceinline__ float bfhi(uint32_t v) {
    uint32_t b = v & 0xffff0000u;
    float f; __builtin_memcpy(&f, &b, 4); return f;
}
__device__ __forceinline__ u16 f2bf(float f) {
    uint32_t x; __builtin_memcpy(&x, &f, 4);
    uint32_t r = (x + 0x7fffu + ((x >> 16) & 1u)) >> 16;
    return (u16)r;
}
__device__ __forceinline__ uint32_t pack2bf(float a, float b) {
    return (uint32_t)f2bf(a) | ((uint32_t)f2bf(b) << 16);
}

// ---------------- sort-based CSR build (no per-edge global atomics) ----------------

__global__ __launch_bounds__(256) void k_bin1(
    const int* __restrict__ src, const int* __restrict__ dst,
    uint32_t* __restrict__ gCur, uint32_t* __restrict__ groupBuf,
    int E, int ngrp, int gcap)
{
    __shared__ uint32_t hcnt[512];
    __shared__ uint32_t hbase[512];
    __shared__ uint32_t hcur[512];
    int nb = gridDim.x;
    int per = (E + nb - 1) / nb;
    int lo = blockIdx.x * per;
    int hi = lo + per; if (hi > E) hi = E;

    for (int t = threadIdx.x; t < ngrp; t += 256) { hcnt[t] = 0; hcur[t] = 0; }
    __syncthreads();

    for (int i = lo + threadIdx.x; i < hi; i += 256)
        atomicAdd(&hcnt[((uint32_t)dst[i]) >> 8], 1u);
    __syncthreads();

    int rot = (blockIdx.x * 37) % (ngrp > 0 ? ngrp : 1);
    for (int k = threadIdx.x; k < ngrp; k += 256) {
        int t = k + rot; if (t >= ngrp) t -= ngrp;
        uint32_t c = hcnt[t];
        hbase[t] = c ? atomicAdd(&gCur[t], c) : 0u;
    }
    __syncthreads();

    for (int i = lo + threadIdx.x; i < hi; i += 256) {
        uint32_t d = (uint32_t)dst[i];
        uint32_t g = d >> 8;
        uint32_t off = hbase[g] + atomicAdd(&hcur[g], 1u);
        if (off < (uint32_t)gcap)
            groupBuf[(size_t)g * gcap + off] = (uint32_t)src[i] | ((d & 255u) << 20);
    }
}

__global__ __launch_bounds__(256) void k_bin2(
    const uint32_t* __restrict__ groupBuf, const uint32_t* __restrict__ gCur,
    uint32_t* __restrict__ bucket, uint32_t* __restrict__ cnt,
    int N, int gcap)
{
    __shared__ uint32_t ncur[256];
    int g = blockIdx.x;
    ncur[threadIdx.x] = 0;
    __syncthreads();
    uint32_t m = gCur[g]; if (m > (uint32_t)gcap) m = gcap;
    int nodebase = g << 8;
    const uint32_t* buf = groupBuf + (size_t)g * gcap;
    for (uint32_t i = threadIdx.x; i < m; i += 256) {
        uint32_t v = buf[i];
        uint32_t nl = v >> 20;
        uint32_t s = v & 0xFFFFFu;
        uint32_t pos = atomicAdd(&ncur[nl], 1u);   // LDS atomic
        if (pos < CAP) bucket[(size_t)(nodebase + (int)nl) * CAP + pos] = s;
    }
    __syncthreads();
    int node = nodebase + threadIdx.x;
    if (node < N) cnt[node] = ncur[threadIdx.x];
}

// ---------------- prep: weight transpose + feature cast + zero rows (one launch) ----

__global__ void k_prep(const float* __restrict__ feat, uint32_t* __restrict__ X0,
                       uint32_t* __restrict__ X1, uint32_t* __restrict__ X2, int N,
                       const float* __restrict__ W1, const float* __restrict__ W2,
                       const float* __restrict__ W3,
                       u16* __restrict__ t0, u16* __restrict__ t1, u16* __restrict__ t2)
{
    int b = blockIdx.x;
    if (b < 3) {
        const float* w = b == 0 ? W1 : (b == 1 ? W2 : W3);
        u16* o = b == 0 ? t0 : (b == 1 ? t1 : t2);
        for (int idx = threadIdx.x; idx < DIM * DIM; idx += blockDim.x) {
            int r = idx >> 7, c = idx & 127;
            o[c * DIM + r] = f2bf(w[idx]);
        }
    } else if (b == 3) {
        int t = threadIdx.x;
        if (t < 64)       X0[(size_t)N * 64 + t] = 0u;
        else if (t < 128) X1[(size_t)N * 64 + (t - 64)] = 0u;
        else if (t < 192) X2[(size_t)N * 64 + (t - 128)] = 0u;
    } else {
        int n4 = N * 32;
        int i = (b - 4) * 256 + threadIdx.x;
        int stride = (gridDim.x - 4) * 256;
        const float4* in4 = (const float4*)feat;
        uint2* out2 = (uint2*)X0;
        for (; i < n4; i += stride) {
            float4 v = in4[i];
            uint2 r;
            r.x = pack2bf(v.x, v.y);
            r.y = pack2bf(v.z, v.w);
            out2[i] = r;
        }
    }
}

// ---------------- fused gather + LN + GEMM ----------------
// Block = 512 thr (8 waves) = 16 nodes. Gather phase: wave w handles nodes
// base+2w, base+2w+1 with the PROVEN r15 structure (scalar addressing, 16-deep,
// interleaved LN). LN result -> LDS (row r = node base+r, 136 u16 stride).
// Barrier. GEMM phase: wave w computes the 16x16 output tile at cols w*16..+15
// (4 MFMAs over K=128), adds bias, ReLU, stores directly to Xout.
// xin/outp must be distinct buffers.

template <int RELU, int OUTF32>
__global__ __launch_bounds__(512) void k_fused(
    const uint32_t* __restrict__ xin, const uint32_t* __restrict__ cnt,
    const uint32_t* __restrict__ bucket,
    const int* __restrict__ src, const int* __restrict__ dst,
    const float* __restrict__ gamma, const float* __restrict__ beta,
    const u16* __restrict__ wt, const float* __restrict__ bias,
    void* __restrict__ outp, int N, int E)
{
    __shared__ uint32_t lds[16 * LROW];
    int w = threadIdx.x >> 6, l = threadIdx.x & 63;
    int base = blockIdx.x * 16;

    // ---- gather phase (identical structure to r15 k_gather_ln) ----
    int node0 = __builtin_amdgcn_readfirstlane(base + 2 * w);
    int node1 = node0 + 1;
    int n0c = node0 < N ? node0 : N - 1;
    int n1c = node1 < N ? node1 : N - 1;
    uint32_t c0 = (node0 < N) ? cnt[n0c] : 0u;
    uint32_t c1 = (node1 < N) ? cnt[n1c] : 0u;
    float a0 = 0.f, a1 = 0.f, b0 = 0.f, b1 = 0.f;

    if (__builtin_expect(c0 > CAP || c1 > CAP, 0)) {
        for (int e = 0; e < E; ++e) {
            int d = dst[e];
            if (d == node0) { uint32_t v = xin[(size_t)src[e] * 64 + l]; a0 += bflo(v); a1 += bfhi(v); }
            else if (d == node1) { uint32_t v = xin[(size_t)src[e] * 64 + l]; b0 += bflo(v); b1 += bfhi(v); }
        }
    } else {
        {
            uint32_t bktv = bucket[(size_t)n0c * CAP + l];
#pragma unroll
            for (int g = 0; g < 4; ++g) {
                if ((uint32_t)(g * 16) < c0) {
                    uint32_t v[16];
#pragma unroll
                    for (int i = 0; i < 16; ++i) {
                        const int SLOT = g * 16 + i;
                        uint32_t su = (uint32_t)__builtin_amdgcn_readfirstlane(
                            (int)((uint32_t)__builtin_amdgcn_readlane(bktv, SLOT)));
                        su = ((uint32_t)SLOT < c0) ? su : (uint32_t)N;
                        v[i] = (xin + (size_t)su * 64)[l];
                    }
#pragma unroll
                    for (int i = 0; i < 16; ++i) { a0 += bflo(v[i]); a1 += bfhi(v[i]); }
                }
            }
        }
        {
            uint32_t bktv = bucket[(size_t)n1c * CAP + l];
#pragma unroll
            for (int g = 0; g < 4; ++g) {
                if ((uint32_t)(g * 16) < c1) {
                    uint32_t v[16];
#pragma unroll
                    for (int i = 0; i < 16; ++i) {
                        const int SLOT = g * 16 + i;
                        uint32_t su = (uint32_t)__builtin_amdgcn_readfirstlane(
                            (int)((uint32_t)__builtin_amdgcn_readlane(bktv, SLOT)));
                        su = ((uint32_t)SLOT < c1) ? su : (uint32_t)N;
                        v[i] = (xin + (size_t)su * 64)[l];
                    }
#pragma unroll
                    for (int i = 0; i < 16; ++i) { b0 += bflo(v[i]); b1 += bfhi(v[i]); }
                }
            }
        }
    }

    float sA = a0 + a1, qA = a0 * a0 + a1 * a1;
    float sB = b0 + b1, qB = b0 * b0 + b1 * b1;
    for (int off = 32; off; off >>= 1) {
        sA += __shfl_xor(sA, off, 64);
        sB += __shfl_xor(sB, off, 64);
        qA += __shfl_xor(qA, off, 64);
        qB += __shfl_xor(qB, off, 64);
    }
    float gg0 = gamma[2 * l], gg1 = gamma[2 * l + 1];
    float bb0 = beta[2 * l],  bb1 = beta[2 * l + 1];
    {
        float mean = sA * (1.f / 128.f);
        float var  = qA * (1.f / 128.f) - mean * mean;
        float rs   = rsqrtf(var + 1e-5f);
        lds[(2 * w) * LROW + l] =
            pack2bf((a0 - mean) * rs * gg0 + bb0, (a1 - mean) * rs * gg1 + bb1);
    }
    {
        float mean = sB * (1.f / 128.f);
        float var  = qB * (1.f / 128.f) - mean * mean;
        float rs   = rsqrtf(var + 1e-5f);
        lds[(2 * w + 1) * LROW + l] =
            pack2bf((b0 - mean) * rs * gg0 + bb0, (b1 - mean) * rs * gg1 + bb1);
    }
    __syncthreads();

    // ---- GEMM phase: wave w -> output cols w*16..w*16+15, rows base..base+15 ----
    int lr = l & 15, lg = l >> 4;
    const u16* ldsu = (const u16*)lds;

    short8 afrag[4];
#pragma unroll
    for (int kc = 0; kc < 4; ++kc)
        afrag[kc] = *(const short8*)&ldsu[lr * (LROW * 2) + kc * 32 + lg * 8];

    int col = w * 16 + lr;
    short8 bfrag[4];
#pragma unroll
    for (int kc = 0; kc < 4; ++kc)
        bfrag[kc] = *(const short8*)(wt + (size_t)col * DIM + kc * 32 + lg * 8);

    f32x4 acc = {0.f, 0.f, 0.f, 0.f};
#pragma unroll
    for (int kc = 0; kc < 4; ++kc)
        acc = __builtin_amdgcn_mfma_f32_16x16x32_bf16(afrag[kc], bfrag[kc], acc, 0, 0, 0);

    float bv = bias[col];
#pragma unroll
    for (int j = 0; j < 4; ++j) {
        int row = base + lg * 4 + j;
        float v = acc[j] + bv;
        if (RELU) v = fmaxf(v, 0.f);
        if (row < N) {
            if (OUTF32) ((float*)outp)[(size_t)row * DIM + col] = v;
            else        ((u16*)outp)[(size_t)row * DIM + col] = f2bf(v);
        }
    }
}

// ---------------- launch ----------------

extern "C" void kernel_launch(void* const* d_in, const int* in_sizes, int n_in,
                              void* d_out, int out_size, void* d_ws, size_t ws_size,
                              hipStream_t stream) {
    const float* feat = (const float*)d_in[0];
    const int* src  = (const int*)d_in[1];
    const int* dst  = (const int*)d_in[2];
    const float* g1 = (const float*)d_in[3],  *be1 = (const float*)d_in[4];
    const float* W1 = (const float*)d_in[5],  *b1  = (const float*)d_in[6];
    const float* g2 = (const float*)d_in[7],  *be2 = (const float*)d_in[8];
    const float* W2 = (const float*)d_in[9],  *b2  = (const float*)d_in[10];
    const float* g3 = (const float*)d_in[11], *be3 = (const float*)d_in[12];
    const float* W3 = (const float*)d_in[13], *b3  = (const float*)d_in[14];

    int N = in_sizes[0] / DIM;
    int E = in_sizes[1];
    float* out = (float*)d_out;

    int ngrp = (N + 255) >> 8;                 // 391 for N=100000 (max 512)
    int gcap = (E / (ngrp > 0 ? ngrp : 1)) * 3 / 2 + 1024;

    char* ws = (char*)d_ws;
    auto alloc = [&](size_t bytes) {
        char* p = ws;
        ws += (bytes + 255) & ~(size_t)255;
        return p;
    };
    uint32_t* gCur     = (uint32_t*)alloc((size_t)ngrp * 4);
    uint32_t* groupBuf = (uint32_t*)alloc((size_t)ngrp * gcap * 4);
    uint32_t* cnt      = (uint32_t*)alloc((size_t)N * 4);
    uint32_t* bucket   = (uint32_t*)alloc((size_t)N * CAP * 4);
    u16* wt1 = (u16*)alloc(DIM * DIM * 2);
    u16* wt2 = (u16*)alloc(DIM * DIM * 2);
    u16* wt3 = (u16*)alloc(DIM * DIM * 2);
    // N+1 rows: row N is the zero row targeted by invalid slots
    uint32_t* X0 = (uint32_t*)alloc((size_t)(N + 1) * 64 * 4);
    uint32_t* X1 = (uint32_t*)alloc((size_t)(N + 1) * 64 * 4);
    uint32_t* X2 = (uint32_t*)alloc((size_t)(N + 1) * 64 * 4);

    hipMemsetAsync(gCur, 0, (size_t)ngrp * 4, stream);
    k_bin1<<<512, 256, 0, stream>>>(src, dst, gCur, groupBuf, E, ngrp, gcap);
    k_bin2<<<ngrp, 256, 0, stream>>>(groupBuf, gCur, bucket, cnt, N, gcap);
    k_prep<<<1028, 256, 0, stream>>>(feat, X0, X1, X2, N, W1, W2, W3, wt1, wt2, wt3);

    int fblocks = (N + 15) / 16;

    // ping-pong: fused kernel never reads and writes the same buffer
    k_fused<1, 0><<<fblocks, 512, 0, stream>>>(X0, cnt, bucket, src, dst, g1, be1, wt1, b1, X1,  N, E);
    k_fused<1, 0><<<fblocks, 512, 0, stream>>>(X1, cnt, bucket, src, dst, g2, be2, wt2, b2, X2,  N, E);
    k_fused<0, 1><<<fblocks, 512, 0, stream>>>(X2, cnt, bucket, src, dst, g3, be3, wt3, b3, out, N, E);
}

// Round 17
// 265.058 us; speedup vs baseline: 1.1695x; 1.0993x over previous
//
#include <hip/hip_runtime.h>
#include <hip/hip_bf16.h>
#include <stdint.h>

typedef unsigned short u16;
typedef __attribute__((ext_vector_type(8))) short short8;
typedef __attribute__((ext_vector_type(4))) float f32x4;

#define DIM 128
#define CAP 64   // per-node bucket capacity; deg ~ Poisson(16), P(deg>=64) ~ 2e-18/node
#define LROW 69  // LDS row stride in u32 (276B): bank=(5lr+4lg)%32 -> <=2-way (free)
#define NB1 512  // bin1 blocks inside merged build kernel

__device__ __forceinline__ float bflo(uint32_t v) {
    uint32_t b = v << 16;
    float f; __builtin_memcpy(&f, &b, 4); return f;
}
__device__ __forceinline__ float bfhi(uint32_t v) {
    uint32_t b = v & 0xffff0000u;
    float f; __builtin_memcpy(&f, &b, 4); return f;
}
__device__ __forceinline__ u16 f2bf(float f) {
    uint32_t x; __builtin_memcpy(&x, &f, 4);
    uint32_t r = (x + 0x7fffu + ((x >> 16) & 1u)) >> 16;
    return (u16)r;
}
__device__ __forceinline__ uint32_t pack2bf(float a, float b) {
    return (uint32_t)f2bf(a) | ((uint32_t)f2bf(b) << 16);
}

// ---------------- merged build: bin1 + weight transpose + cast + zero rows ----------
// blocks [0,NB1): bin1 coarse-binning; [NB1,NB1+3): W transpose; NB1+3: zero rows;
// [NB1+4, grid): feature cast. All parts independent -> overlap in one dispatch.

__global__ __launch_bounds__(256) void k_build(
    const int* __restrict__ src, const int* __restrict__ dst,
    uint32_t* __restrict__ gCur, uint32_t* __restrict__ groupBuf,
    int E, int ngrp, int gcap,
    const float* __restrict__ feat, uint32_t* __restrict__ X0,
    uint32_t* __restrict__ X1, uint32_t* __restrict__ X2, int N,
    const float* __restrict__ W1, const float* __restrict__ W2,
    const float* __restrict__ W3,
    u16* __restrict__ t0, u16* __restrict__ t1, u16* __restrict__ t2)
{
    int b = blockIdx.x;
    if (b < NB1) {
        __shared__ uint32_t hcnt[512];
        __shared__ uint32_t hbase[512];
        __shared__ uint32_t hcur[512];
        int per = (E + NB1 - 1) / NB1;
        int lo = b * per;
        int hi = lo + per; if (hi > E) hi = E;

        for (int t = threadIdx.x; t < ngrp; t += 256) { hcnt[t] = 0; hcur[t] = 0; }
        __syncthreads();

        for (int i = lo + threadIdx.x; i < hi; i += 256)
            atomicAdd(&hcnt[((uint32_t)dst[i]) >> 8], 1u);
        __syncthreads();

        int rot = (b * 37) % (ngrp > 0 ? ngrp : 1);
        for (int k = threadIdx.x; k < ngrp; k += 256) {
            int t = k + rot; if (t >= ngrp) t -= ngrp;
            uint32_t c = hcnt[t];
            hbase[t] = c ? atomicAdd(&gCur[t], c) : 0u;
        }
        __syncthreads();

        for (int i = lo + threadIdx.x; i < hi; i += 256) {
            uint32_t d = (uint32_t)dst[i];
            uint32_t g = d >> 8;
            uint32_t off = hbase[g] + atomicAdd(&hcur[g], 1u);
            if (off < (uint32_t)gcap)
                groupBuf[(size_t)g * gcap + off] = (uint32_t)src[i] | ((d & 255u) << 20);
        }
    } else if (b < NB1 + 3) {
        int wi = b - NB1;
        const float* w = wi == 0 ? W1 : (wi == 1 ? W2 : W3);
        u16* o = wi == 0 ? t0 : (wi == 1 ? t1 : t2);
        for (int idx = threadIdx.x; idx < DIM * DIM; idx += blockDim.x) {
            int r = idx >> 7, c = idx & 127;
            o[c * DIM + r] = f2bf(w[idx]);
        }
    } else if (b == NB1 + 3) {
        int t = threadIdx.x;
        if (t < 64)       X0[(size_t)N * 64 + t] = 0u;
        else if (t < 128) X1[(size_t)N * 64 + (t - 64)] = 0u;
        else if (t < 192) X2[(size_t)N * 64 + (t - 128)] = 0u;
    } else {
        int n4 = N * 32;
        int i = (b - (NB1 + 4)) * 256 + threadIdx.x;
        int stride = (gridDim.x - (NB1 + 4)) * 256;
        const float4* in4 = (const float4*)feat;
        uint2* out2 = (uint2*)X0;
        for (; i < n4; i += stride) {
            float4 v = in4[i];
            uint2 r;
            r.x = pack2bf(v.x, v.y);
            r.y = pack2bf(v.z, v.w);
            out2[i] = r;
        }
    }
}

// ---------------- bin2: scatter group records into per-node buckets ----------------

__global__ __launch_bounds__(512) void k_bin2(
    const uint32_t* __restrict__ groupBuf, const uint32_t* __restrict__ gCur,
    uint32_t* __restrict__ bucket, uint32_t* __restrict__ cnt,
    int N, int gcap)
{
    __shared__ uint32_t ncur[256];
    int g = blockIdx.x;
    if (threadIdx.x < 256) ncur[threadIdx.x] = 0;
    __syncthreads();
    uint32_t m = gCur[g]; if (m > (uint32_t)gcap) m = gcap;
    int nodebase = g << 8;
    const uint32_t* buf = groupBuf + (size_t)g * gcap;
    for (uint32_t i = threadIdx.x; i < m; i += 512) {
        uint32_t v = buf[i];
        uint32_t nl = v >> 20;
        uint32_t s = v & 0xFFFFFu;
        uint32_t pos = atomicAdd(&ncur[nl], 1u);   // LDS atomic
        if (pos < CAP) bucket[(size_t)(nodebase + (int)nl) * CAP + pos] = s;
    }
    __syncthreads();
    int node = nodebase + threadIdx.x;
    if (threadIdx.x < 256 && node < N) cnt[node] = ncur[threadIdx.x];
}

// ---------------- fused gather + LN + GEMM ----------------
// Block = 512 thr (8 waves) = 16 nodes. B-fragments + bias hoisted BEFORE the
// gather phase. Gather: proven scalar-addressed 16-deep, 2 nodes/wave,
// interleaved LN -> LDS. Barrier. GEMM: wave w does cols w*16..+15 (4 MFMAs),
// stores directly. xin/outp must be distinct buffers.

template <int RELU, int OUTF32>
__global__ __launch_bounds__(512) void k_fused(
    const uint32_t* __restrict__ xin, const uint32_t* __restrict__ cnt,
    const uint32_t* __restrict__ bucket,
    const int* __restrict__ src, const int* __restrict__ dst,
    const float* __restrict__ gamma, const float* __restrict__ beta,
    const u16* __restrict__ wt, const float* __restrict__ bias,
    void* __restrict__ outp, int N, int E)
{
    __shared__ uint32_t lds[16 * LROW];
    int w = threadIdx.x >> 6, l = threadIdx.x & 63;
    int base = blockIdx.x * 16;
    int lr = l & 15, lg = l >> 4;

    // ---- hoisted GEMM operands (independent of gather; issue early) ----
    int col = w * 16 + lr;
    short8 bfrag[4];
#pragma unroll
    for (int kc = 0; kc < 4; ++kc)
        bfrag[kc] = *(const short8*)(wt + (size_t)col * DIM + kc * 32 + lg * 8);
    float bv = bias[col];

    // ---- gather phase (r15-proven structure) ----
    int node0 = __builtin_amdgcn_readfirstlane(base + 2 * w);
    int node1 = node0 + 1;
    int n0c = node0 < N ? node0 : N - 1;
    int n1c = node1 < N ? node1 : N - 1;
    uint32_t c0 = (node0 < N) ? cnt[n0c] : 0u;
    uint32_t c1 = (node1 < N) ? cnt[n1c] : 0u;
    float a0 = 0.f, a1 = 0.f, b0 = 0.f, b1 = 0.f;

    if (__builtin_expect(c0 > CAP || c1 > CAP, 0)) {
        for (int e = 0; e < E; ++e) {
            int d = dst[e];
            if (d == node0) { uint32_t v = xin[(size_t)src[e] * 64 + l]; a0 += bflo(v); a1 += bfhi(v); }
            else if (d == node1) { uint32_t v = xin[(size_t)src[e] * 64 + l]; b0 += bflo(v); b1 += bfhi(v); }
        }
    } else {
        {
            uint32_t bktv = bucket[(size_t)n0c * CAP + l];
#pragma unroll
            for (int g = 0; g < 4; ++g) {
                if ((uint32_t)(g * 16) < c0) {
                    uint32_t v[16];
#pragma unroll
                    for (int i = 0; i < 16; ++i) {
                        const int SLOT = g * 16 + i;
                        uint32_t su = (uint32_t)__builtin_amdgcn_readfirstlane(
                            (int)((uint32_t)__builtin_amdgcn_readlane(bktv, SLOT)));
                        su = ((uint32_t)SLOT < c0) ? su : (uint32_t)N;
                        v[i] = (xin + (size_t)su * 64)[l];
                    }
#pragma unroll
                    for (int i = 0; i < 16; ++i) { a0 += bflo(v[i]); a1 += bfhi(v[i]); }
                }
            }
        }
        {
            uint32_t bktv = bucket[(size_t)n1c * CAP + l];
#pragma unroll
            for (int g = 0; g < 4; ++g) {
                if ((uint32_t)(g * 16) < c1) {
                    uint32_t v[16];
#pragma unroll
                    for (int i = 0; i < 16; ++i) {
                        const int SLOT = g * 16 + i;
                        uint32_t su = (uint32_t)__builtin_amdgcn_readfirstlane(
                            (int)((uint32_t)__builtin_amdgcn_readlane(bktv, SLOT)));
                        su = ((uint32_t)SLOT < c1) ? su : (uint32_t)N;
                        v[i] = (xin + (size_t)su * 64)[l];
                    }
#pragma unroll
                    for (int i = 0; i < 16; ++i) { b0 += bflo(v[i]); b1 += bfhi(v[i]); }
                }
            }
        }
    }

    float sA = a0 + a1, qA = a0 * a0 + a1 * a1;
    float sB = b0 + b1, qB = b0 * b0 + b1 * b1;
    for (int off = 32; off; off >>= 1) {
        sA += __shfl_xor(sA, off, 64);
        sB += __shfl_xor(sB, off, 64);
        qA += __shfl_xor(qA, off, 64);
        qB += __shfl_xor(qB, off, 64);
    }
    float gg0 = gamma[2 * l], gg1 = gamma[2 * l + 1];
    float bb0 = beta[2 * l],  bb1 = beta[2 * l + 1];
    {
        float mean = sA * (1.f / 128.f);
        float var  = qA * (1.f / 128.f) - mean * mean;
        float rs   = rsqrtf(var + 1e-5f);
        lds[(2 * w) * LROW + l] =
            pack2bf((a0 - mean) * rs * gg0 + bb0, (a1 - mean) * rs * gg1 + bb1);
    }
    {
        float mean = sB * (1.f / 128.f);
        float var  = qB * (1.f / 128.f) - mean * mean;
        float rs   = rsqrtf(var + 1e-5f);
        lds[(2 * w + 1) * LROW + l] =
            pack2bf((b0 - mean) * rs * gg0 + bb0, (b1 - mean) * rs * gg1 + bb1);
    }
    __syncthreads();

    // ---- GEMM phase: pure LDS + MFMA + store ----
    const u16* ldsu = (const u16*)lds;
    short8 afrag[4];
#pragma unroll
    for (int kc = 0; kc < 4; ++kc)
        afrag[kc] = *(const short8*)&ldsu[lr * (LROW * 2) + kc * 32 + lg * 8];

    f32x4 acc = {0.f, 0.f, 0.f, 0.f};
#pragma unroll
    for (int kc = 0; kc < 4; ++kc)
        acc = __builtin_amdgcn_mfma_f32_16x16x32_bf16(afrag[kc], bfrag[kc], acc, 0, 0, 0);

#pragma unroll
    for (int j = 0; j < 4; ++j) {
        int row = base + lg * 4 + j;
        float v = acc[j] + bv;
        if (RELU) v = fmaxf(v, 0.f);
        if (row < N) {
            if (OUTF32) ((float*)outp)[(size_t)row * DIM + col] = v;
            else        ((u16*)outp)[(size_t)row * DIM + col] = f2bf(v);
        }
    }
}

// ---------------- launch ----------------

extern "C" void kernel_launch(void* const* d_in, const int* in_sizes, int n_in,
                              void* d_out, int out_size, void* d_ws, size_t ws_size,
                              hipStream_t stream) {
    const float* feat = (const float*)d_in[0];
    const int* src  = (const int*)d_in[1];
    const int* dst  = (const int*)d_in[2];
    const float* g1 = (const float*)d_in[3],  *be1 = (const float*)d_in[4];
    const float* W1 = (const float*)d_in[5],  *b1  = (const float*)d_in[6];
    const float* g2 = (const float*)d_in[7],  *be2 = (const float*)d_in[8];
    const float* W2 = (const float*)d_in[9],  *b2  = (const float*)d_in[10];
    const float* g3 = (const float*)d_in[11], *be3 = (const float*)d_in[12];
    const float* W3 = (const float*)d_in[13], *b3  = (const float*)d_in[14];

    int N = in_sizes[0] / DIM;
    int E = in_sizes[1];
    float* out = (float*)d_out;

    int ngrp = (N + 255) >> 8;                 // 391 for N=100000 (max 512)
    int gcap = (E / (ngrp > 0 ? ngrp : 1)) * 3 / 2 + 1024;

    char* ws = (char*)d_ws;
    auto alloc = [&](size_t bytes) {
        char* p = ws;
        ws += (bytes + 255) & ~(size_t)255;
        return p;
    };
    uint32_t* gCur     = (uint32_t*)alloc((size_t)ngrp * 4);
    uint32_t* groupBuf = (uint32_t*)alloc((size_t)ngrp * gcap * 4);
    uint32_t* cnt      = (uint32_t*)alloc((size_t)N * 4);
    uint32_t* bucket   = (uint32_t*)alloc((size_t)N * CAP * 4);
    u16* wt1 = (u16*)alloc(DIM * DIM * 2);
    u16* wt2 = (u16*)alloc(DIM * DIM * 2);
    u16* wt3 = (u16*)alloc(DIM * DIM * 2);
    // N+1 rows: row N is the zero row targeted by invalid slots
    uint32_t* X0 = (uint32_t*)alloc((size_t)(N + 1) * 64 * 4);
    uint32_t* X1 = (uint32_t*)alloc((size_t)(N + 1) * 64 * 4);
    uint32_t* X2 = (uint32_t*)alloc((size_t)(N + 1) * 64 * 4);

    hipMemsetAsync(gCur, 0, (size_t)ngrp * 4, stream);
    k_build<<<NB1 + 4 + 1024, 256, 0, stream>>>(src, dst, gCur, groupBuf, E, ngrp, gcap,
                                                feat, X0, X1, X2, N, W1, W2, W3, wt1, wt2, wt3);
    k_bin2<<<ngrp, 512, 0, stream>>>(groupBuf, gCur, bucket, cnt, N, gcap);

    int fblocks = (N + 15) / 16;

    // ping-pong: fused kernel never reads and writes the same buffer
    k_fused<1, 0><<<fblocks, 512, 0, stream>>>(X0, cnt, bucket, src, dst, g1, be1, wt1, b1, X1,  N, E);
    k_fused<1, 0><<<fblocks, 512, 0, stream>>>(X1, cnt, bucket, src, dst, g2, be2, wt2, b2, X2,  N, E);
    k_fused<0, 1><<<fblocks, 512, 0, stream>>>(X2, cnt, bucket, src, dst, g3, be3, wt3, b3, out, N, E);
}

// Round 18
// 255.069 us; speedup vs baseline: 1.2153x; 1.0392x over previous
//
#include <hip/hip_runtime.h>
#include <hip/hip_bf16.h>
#include <stdint.h>

typedef unsigned short u16;
typedef __attribute__((ext_vector_type(8))) short short8;
typedef __attribute__((ext_vector_type(4))) float f32x4;

#define DIM 128
#define CAP 64   // per-node bucket capacity; deg ~ Poisson(16), P(deg>=64) ~ 2e-18/node
#define LROW 69  // LDS row stride in u32 (276B): bank=(5lr+4lg)%32 -> <=2-way (free)
#define NB1 512  // bin1 blocks inside merged build kernel
#define STAGE 3328  // LDS staging capacity (>= ceil(E/NB1) for E<=1.7M)

__device__ __forceinline__ float bflo(uint32_t v) {
    uint32_t b = v << 16;
    float f; __builtin_memcpy(&f, &b, 4); return f;
}
__device__ __forceinline__ float bfhi(uint32_t v) {
    uint32_t b = v & 0xffff0000u;
    float f; __builtin_memcpy(&f, &b, 4); return f;
}
__device__ __forceinline__ u16 f2bf(float f) {
    uint32_t x; __builtin_memcpy(&x, &f, 4);
    uint32_t r = (x + 0x7fffu + ((x >> 16) & 1u)) >> 16;
    return (u16)r;
}
__device__ __forceinline__ uint32_t pack2bf(float a, float b) {
    return (uint32_t)f2bf(a) | ((uint32_t)f2bf(b) << 16);
}

// ---------------- merged build: bin1 (counting-sort) + transpose + cast + zero ------
// blocks [0,NB1): bin1 with LDS staging -> group-major ordered copy-out
// (piecewise-contiguous global writes instead of random 4B scatter);
// [NB1,NB1+3): W transpose; NB1+3: zero rows; rest: feature cast.

__global__ __launch_bounds__(256) void k_build(
    const int* __restrict__ src, const int* __restrict__ dst,
    uint32_t* __restrict__ gCur, uint32_t* __restrict__ groupBuf,
    int E, int ngrp, int gcap,
    const float* __restrict__ feat, uint32_t* __restrict__ X0,
    uint32_t* __restrict__ X1, uint32_t* __restrict__ X2, int N,
    const float* __restrict__ W1, const float* __restrict__ W2,
    const float* __restrict__ W3,
    u16* __restrict__ t0, u16* __restrict__ t1, u16* __restrict__ t2)
{
    __shared__ uint32_t hcnt[512];
    __shared__ uint32_t hbase[512];
    __shared__ uint32_t lbase[512];
    __shared__ uint32_t hcur[512];
    __shared__ uint32_t psum[256];
    __shared__ uint32_t sval[STAGE];
    __shared__ uint32_t starg[STAGE];

    int b = blockIdx.x;
    if (b < NB1) {
        int per = (E + NB1 - 1) / NB1;
        int lo = b * per;
        int hi = lo + per; if (hi > E) hi = E;
        int cntE = hi - lo;
        int t = threadIdx.x;

        for (int k = t; k < 512; k += 256) { hcnt[k] = 0; hcur[k] = 0; }
        __syncthreads();

        // phase A: LDS histogram of coarse groups
        for (int i = lo + t; i < hi; i += 256)
            atomicAdd(&hcnt[((uint32_t)dst[i]) >> 8], 1u);
        __syncthreads();

        // phase B1: reserve global space per (block, group); rotate to de-contend
        int rot = (b * 37) % (ngrp > 0 ? ngrp : 1);
        for (int k = t; k < ngrp; k += 256) {
            int g = k + rot; if (g >= ngrp) g -= ngrp;
            uint32_t c = hcnt[g];
            hbase[g] = c ? atomicAdd(&gCur[g], c) : 0u;
        }
        // phase B2: local exclusive scan of hcnt (512 entries, pairwise + 256-scan)
        uint32_t ea = hcnt[2 * t], eb = hcnt[2 * t + 1];
        psum[t] = ea + eb;
        __syncthreads();
        for (int off = 1; off < 256; off <<= 1) {
            uint32_t u = (t >= off) ? psum[t - off] : 0u;
            __syncthreads();
            psum[t] += u;
            __syncthreads();
        }
        uint32_t ex = psum[t] - (ea + eb);
        lbase[2 * t] = ex;
        lbase[2 * t + 1] = ex + ea;
        __syncthreads();

        if (cntE <= STAGE) {
            // phase C: scatter into LDS staging, group-major; record final target
            for (int i = lo + t; i < hi; i += 256) {
                uint32_t d = (uint32_t)dst[i];
                uint32_t g = d >> 8;
                uint32_t pos = atomicAdd(&hcur[g], 1u);
                uint32_t li = lbase[g] + pos;
                uint32_t go = hbase[g] + pos;
                sval[li] = (uint32_t)src[i] | ((d & 255u) << 20);
                starg[li] = (go < (uint32_t)gcap)
                              ? (uint32_t)(g * (uint32_t)gcap + go) : 0xFFFFFFFFu;
            }
            __syncthreads();
            // phase D: ordered copy-out — piecewise-contiguous global writes
            for (int i = t; i < cntE; i += 256) {
                uint32_t tg = starg[i];
                if (tg != 0xFFFFFFFFu) groupBuf[tg] = sval[i];
            }
        } else {
            // fallback: direct scatter (generic E)
            for (int i = lo + t; i < hi; i += 256) {
                uint32_t d = (uint32_t)dst[i];
                uint32_t g = d >> 8;
                uint32_t off = hbase[g] + atomicAdd(&hcur[g], 1u);
                if (off < (uint32_t)gcap)
                    groupBuf[(size_t)g * gcap + off] = (uint32_t)src[i] | ((d & 255u) << 20);
            }
        }
    } else if (b < NB1 + 3) {
        int wi = b - NB1;
        const float* w = wi == 0 ? W1 : (wi == 1 ? W2 : W3);
        u16* o = wi == 0 ? t0 : (wi == 1 ? t1 : t2);
        for (int idx = threadIdx.x; idx < DIM * DIM; idx += blockDim.x) {
            int r = idx >> 7, c = idx & 127;
            o[c * DIM + r] = f2bf(w[idx]);
        }
    } else if (b == NB1 + 3) {
        int t = threadIdx.x;
        if (t < 64)       X0[(size_t)N * 64 + t] = 0u;
        else if (t < 128) X1[(size_t)N * 64 + (t - 64)] = 0u;
        else if (t < 192) X2[(size_t)N * 64 + (t - 128)] = 0u;
    } else {
        int n4 = N * 32;
        int i = (b - (NB1 + 4)) * 256 + threadIdx.x;
        int stride = (gridDim.x - (NB1 + 4)) * 256;
        const float4* in4 = (const float4*)feat;
        uint2* out2 = (uint2*)X0;
        for (; i < n4; i += stride) {
            float4 v = in4[i];
            uint2 r;
            r.x = pack2bf(v.x, v.y);
            r.y = pack2bf(v.z, v.w);
            out2[i] = r;
        }
    }
}

// ---------------- bin2: scatter group records into per-node buckets ----------------

__global__ __launch_bounds__(512) void k_bin2(
    const uint32_t* __restrict__ groupBuf, const uint32_t* __restrict__ gCur,
    uint32_t* __restrict__ bucket, uint32_t* __restrict__ cnt,
    int N, int gcap)
{
    __shared__ uint32_t ncur[256];
    int g = blockIdx.x;
    if (threadIdx.x < 256) ncur[threadIdx.x] = 0;
    __syncthreads();
    uint32_t m = gCur[g]; if (m > (uint32_t)gcap) m = gcap;
    int nodebase = g << 8;
    const uint32_t* buf = groupBuf + (size_t)g * gcap;
    for (uint32_t i = threadIdx.x; i < m; i += 512) {
        uint32_t v = buf[i];
        uint32_t nl = v >> 20;
        uint32_t s = v & 0xFFFFFu;
        uint32_t pos = atomicAdd(&ncur[nl], 1u);   // LDS atomic
        if (pos < CAP) bucket[(size_t)(nodebase + (int)nl) * CAP + pos] = s;
    }
    __syncthreads();
    int node = nodebase + threadIdx.x;
    if (threadIdx.x < 256 && node < N) cnt[node] = ncur[threadIdx.x];
}

// ---------------- fused gather + LN + GEMM (r17-proven) ----------------

template <int RELU, int OUTF32>
__global__ __launch_bounds__(512) void k_fused(
    const uint32_t* __restrict__ xin, const uint32_t* __restrict__ cnt,
    const uint32_t* __restrict__ bucket,
    const int* __restrict__ src, const int* __restrict__ dst,
    const float* __restrict__ gamma, const float* __restrict__ beta,
    const u16* __restrict__ wt, const float* __restrict__ bias,
    void* __restrict__ outp, int N, int E)
{
    __shared__ uint32_t lds[16 * LROW];
    int w = threadIdx.x >> 6, l = threadIdx.x & 63;
    int base = blockIdx.x * 16;
    int lr = l & 15, lg = l >> 4;

    // hoisted GEMM operands (independent of gather; issue early)
    int col = w * 16 + lr;
    short8 bfrag[4];
#pragma unroll
    for (int kc = 0; kc < 4; ++kc)
        bfrag[kc] = *(const short8*)(wt + (size_t)col * DIM + kc * 32 + lg * 8);
    float bv = bias[col];

    // gather phase (scalar-addressed, 16-deep, 2 nodes/wave)
    int node0 = __builtin_amdgcn_readfirstlane(base + 2 * w);
    int node1 = node0 + 1;
    int n0c = node0 < N ? node0 : N - 1;
    int n1c = node1 < N ? node1 : N - 1;
    uint32_t c0 = (node0 < N) ? cnt[n0c] : 0u;
    uint32_t c1 = (node1 < N) ? cnt[n1c] : 0u;
    float a0 = 0.f, a1 = 0.f, b0 = 0.f, b1 = 0.f;

    if (__builtin_expect(c0 > CAP || c1 > CAP, 0)) {
        for (int e = 0; e < E; ++e) {
            int d = dst[e];
            if (d == node0) { uint32_t v = xin[(size_t)src[e] * 64 + l]; a0 += bflo(v); a1 += bfhi(v); }
            else if (d == node1) { uint32_t v = xin[(size_t)src[e] * 64 + l]; b0 += bflo(v); b1 += bfhi(v); }
        }
    } else {
        {
            uint32_t bktv = bucket[(size_t)n0c * CAP + l];
#pragma unroll
            for (int g = 0; g < 4; ++g) {
                if ((uint32_t)(g * 16) < c0) {
                    uint32_t v[16];
#pragma unroll
                    for (int i = 0; i < 16; ++i) {
                        const int SLOT = g * 16 + i;
                        uint32_t su = (uint32_t)__builtin_amdgcn_readfirstlane(
                            (int)((uint32_t)__builtin_amdgcn_readlane(bktv, SLOT)));
                        su = ((uint32_t)SLOT < c0) ? su : (uint32_t)N;
                        v[i] = (xin + (size_t)su * 64)[l];
                    }
#pragma unroll
                    for (int i = 0; i < 16; ++i) { a0 += bflo(v[i]); a1 += bfhi(v[i]); }
                }
            }
        }
        {
            uint32_t bktv = bucket[(size_t)n1c * CAP + l];
#pragma unroll
            for (int g = 0; g < 4; ++g) {
                if ((uint32_t)(g * 16) < c1) {
                    uint32_t v[16];
#pragma unroll
                    for (int i = 0; i < 16; ++i) {
                        const int SLOT = g * 16 + i;
                        uint32_t su = (uint32_t)__builtin_amdgcn_readfirstlane(
                            (int)((uint32_t)__builtin_amdgcn_readlane(bktv, SLOT)));
                        su = ((uint32_t)SLOT < c1) ? su : (uint32_t)N;
                        v[i] = (xin + (size_t)su * 64)[l];
                    }
#pragma unroll
                    for (int i = 0; i < 16; ++i) { b0 += bflo(v[i]); b1 += bfhi(v[i]); }
                }
            }
        }
    }

    float sA = a0 + a1, qA = a0 * a0 + a1 * a1;
    float sB = b0 + b1, qB = b0 * b0 + b1 * b1;
    for (int off = 32; off; off >>= 1) {
        sA += __shfl_xor(sA, off, 64);
        sB += __shfl_xor(sB, off, 64);
        qA += __shfl_xor(qA, off, 64);
        qB += __shfl_xor(qB, off, 64);
    }
    float gg0 = gamma[2 * l], gg1 = gamma[2 * l + 1];
    float bb0 = beta[2 * l],  bb1 = beta[2 * l + 1];
    {
        float mean = sA * (1.f / 128.f);
        float var  = qA * (1.f / 128.f) - mean * mean;
        float rs   = rsqrtf(var + 1e-5f);
        lds[(2 * w) * LROW + l] =
            pack2bf((a0 - mean) * rs * gg0 + bb0, (a1 - mean) * rs * gg1 + bb1);
    }
    {
        float mean = sB * (1.f / 128.f);
        float var  = qB * (1.f / 128.f) - mean * mean;
        float rs   = rsqrtf(var + 1e-5f);
        lds[(2 * w + 1) * LROW + l] =
            pack2bf((b0 - mean) * rs * gg0 + bb0, (b1 - mean) * rs * gg1 + bb1);
    }
    __syncthreads();

    // GEMM phase: pure LDS + MFMA + store
    const u16* ldsu = (const u16*)lds;
    short8 afrag[4];
#pragma unroll
    for (int kc = 0; kc < 4; ++kc)
        afrag[kc] = *(const short8*)&ldsu[lr * (LROW * 2) + kc * 32 + lg * 8];

    f32x4 acc = {0.f, 0.f, 0.f, 0.f};
#pragma unroll
    for (int kc = 0; kc < 4; ++kc)
        acc = __builtin_amdgcn_mfma_f32_16x16x32_bf16(afrag[kc], bfrag[kc], acc, 0, 0, 0);

#pragma unroll
    for (int j = 0; j < 4; ++j) {
        int row = base + lg * 4 + j;
        float v = acc[j] + bv;
        if (RELU) v = fmaxf(v, 0.f);
        if (row < N) {
            if (OUTF32) ((float*)outp)[(size_t)row * DIM + col] = v;
            else        ((u16*)outp)[(size_t)row * DIM + col] = f2bf(v);
        }
    }
}

// ---------------- launch ----------------

extern "C" void kernel_launch(void* const* d_in, const int* in_sizes, int n_in,
                              void* d_out, int out_size, void* d_ws, size_t ws_size,
                              hipStream_t stream) {
    const float* feat = (const float*)d_in[0];
    const int* src  = (const int*)d_in[1];
    const int* dst  = (const int*)d_in[2];
    const float* g1 = (const float*)d_in[3],  *be1 = (const float*)d_in[4];
    const float* W1 = (const float*)d_in[5],  *b1  = (const float*)d_in[6];
    const float* g2 = (const float*)d_in[7],  *be2 = (const float*)d_in[8];
    const float* W2 = (const float*)d_in[9],  *b2  = (const float*)d_in[10];
    const float* g3 = (const float*)d_in[11], *be3 = (const float*)d_in[12];
    const float* W3 = (const float*)d_in[13], *b3  = (const float*)d_in[14];

    int N = in_sizes[0] / DIM;
    int E = in_sizes[1];
    float* out = (float*)d_out;

    int ngrp = (N + 255) >> 8;                 // 391 for N=100000 (max 512)
    int gcap = (E / (ngrp > 0 ? ngrp : 1)) * 3 / 2 + 1024;

    char* ws = (char*)d_ws;
    auto alloc = [&](size_t bytes) {
        char* p = ws;
        ws += (bytes + 255) & ~(size_t)255;
        return p;
    };
    uint32_t* gCur     = (uint32_t*)alloc((size_t)ngrp * 4);
    uint32_t* groupBuf = (uint32_t*)alloc((size_t)ngrp * gcap * 4);
    uint32_t* cnt      = (uint32_t*)alloc((size_t)N * 4);
    uint32_t* bucket   = (uint32_t*)alloc((size_t)N * CAP * 4);
    u16* wt1 = (u16*)alloc(DIM * DIM * 2);
    u16* wt2 = (u16*)alloc(DIM * DIM * 2);
    u16* wt3 = (u16*)alloc(DIM * DIM * 2);
    // N+1 rows: row N is the zero row targeted by invalid slots
    uint32_t* X0 = (uint32_t*)alloc((size_t)(N + 1) * 64 * 4);
    uint32_t* X1 = (uint32_t*)alloc((size_t)(N + 1) * 64 * 4);
    uint32_t* X2 = (uint32_t*)alloc((size_t)(N + 1) * 64 * 4);

    hipMemsetAsync(gCur, 0, (size_t)ngrp * 4, stream);
    k_build<<<NB1 + 4 + 1024, 256, 0, stream>>>(src, dst, gCur, groupBuf, E, ngrp, gcap,
                                                feat, X0, X1, X2, N, W1, W2, W3, wt1, wt2, wt3);
    k_bin2<<<ngrp, 512, 0, stream>>>(groupBuf, gCur, bucket, cnt, N, gcap);

    int fblocks = (N + 15) / 16;

    // ping-pong: fused kernel never reads and writes the same buffer
    k_fused<1, 0><<<fblocks, 512, 0, stream>>>(X0, cnt, bucket, src, dst, g1, be1, wt1, b1, X1,  N, E);
    k_fused<1, 0><<<fblocks, 512, 0, stream>>>(X1, cnt, bucket, src, dst, g2, be2, wt2, b2, X2,  N, E);
    k_fused<0, 1><<<fblocks, 512, 0, stream>>>(X2, cnt, bucket, src, dst, g3, be3, wt3, b3, out, N, E);
}